// Round 10
// baseline (5350.372 us; speedup 1.0000x reference)
//
#include <hip/hip_runtime.h>
#include <math.h>

#define N_TOKENS 16384
#define D_MODEL  4096
#define N_EXP    64

#define TOKB  64                 // tokens per block (lane = token)
#define NWV   16                 // waves per block (1024 threads)
#define NSL   8                  // k-slices
#define KSL   (D_MODEL / NSL)    // 512 k per wave
#define CH    16                 // k per chunk (= 64 B per-lane line)
#define NCH   (KSL / CH)         // 32 chunks
#define PPAD  36                 // partial-tile expert stride (conflict-free)
#define PFOFF (NWV * TOKB * PPAD) // 36864 floats
#define NBLK  (N_TOKENS / TOKB)  // 256 blocks = 1/CU -> 16 waves/CU = 4/SIMD

// ---------------------------------------------------------------------------
// Pre-pass: w[64][4096] -> wT[4096][64] (k-major). A k-row's 64 experts are
// contiguous -> per-k expert-half = 32 uniform floats -> s_load_dwordx16.
// ---------------------------------------------------------------------------
__global__ void __launch_bounds__(256)
transpose_w(const float* __restrict__ w, float* __restrict__ wt) {
    __shared__ float t[64][65];
    const int k0 = blockIdx.x * 64;
    const int kc = (threadIdx.x & 15) * 4;
    const int e0 = threadIdx.x >> 4;         // 0..15
#pragma unroll
    for (int p = 0; p < 4; ++p) {
        int e = p * 16 + e0;
        float4 v = *(const float4*)(w + (size_t)e * D_MODEL + k0 + kc);
        t[kc + 0][e] = v.x; t[kc + 1][e] = v.y;
        t[kc + 2][e] = v.z; t[kc + 3][e] = v.w;
    }
    __syncthreads();
    const int kr = threadIdx.x >> 2;         // 0..63
    const int ec = (threadIdx.x & 3) * 16;
#pragma unroll
    for (int j = 0; j < 4; ++j) {
        float4 v = make_float4(t[kr][ec + j * 4 + 0], t[kr][ec + j * 4 + 1],
                               t[kr][ec + j * 4 + 2], t[kr][ec + j * 4 + 3]);
        *(float4*)(wt + (size_t)(k0 + kr) * N_EXP + ec + j * 4) = v;
    }
}

// ---------------------------------------------------------------------------
// Fused router — round-8 structure with the prefetch made un-droppable.
// Round 8's VALU-busy TIME was 63 us ~= the 54.6 us FMA floor (instruction
// stream near-ideal); its loss was the compiler sinking the guarded
// `if (g+1<NCH)` prefetch (VGPR=52 proves it) -> serial HBM latency/chunk.
// Round 9's LDS x-path poisoned the lgkmcnt stream (ds_read forces
// lgkmcnt(0), draining all w s_loads per k-row) -> VALU time 254 us. So:
//   - lane = token; x via per-lane global_load_dwordx4 (vector path)
//   - w via scalar pipe: per k-row 32 uniform floats from L2-hot wT
//   - NO DS ops in the main loop (SMEM waits stay precise)
//   - g-loop hand-unrolled x2, UNCONDITIONAL prefetch with wrapped index
//     ((g+2)&31 -> always in-bounds; last iter re-reads chunk 0 from L1).
//     Loads are issued one full 512-FMA block before their use.
// Epilogue (verbatim round 8): 16 partial tiles [64 tok][32 exp] stride 36
// in LDS, 8-slice reduce, ballot-argmax softmax/top-2, per-block p/f sums.
// ---------------------------------------------------------------------------
__global__ void __launch_bounds__(1024)
router_fused(const float* __restrict__ x, const float* __restrict__ wt,
             float* __restrict__ out, float* __restrict__ block_sums) {
    __shared__ float part[PFOFF + 2 * NWV * 64];   // 147456 + 8192 B

    const int tid  = threadIdx.x;
    const int wid  = tid >> 6;
    const int lane = tid & 63;               // token within block
    const int tok0 = blockIdx.x * TOKB;

    const int wid_u = __builtin_amdgcn_readfirstlane(wid);
    const int h = wid_u & 1;                 // expert half: experts h*32..+31
    const int s = wid_u >> 1;                // k-slice: k in [s*512, s*512+512)

    const float* xr = x + (size_t)(tok0 + lane) * D_MODEL + s * KSL;
    const float* wr = wt + (size_t)s * KSL * N_EXP + h * 32;   // uniform

    float acc[32] = {};

    auto fma_chunk = [&](float4 a0, float4 a1, float4 a2, float4 a3, int g) {
        const float xc[CH] = {a0.x, a0.y, a0.z, a0.w,
                              a1.x, a1.y, a1.z, a1.w,
                              a2.x, a2.y, a2.z, a2.w,
                              a3.x, a3.y, a3.z, a3.w};
        const float* wg = wr + (size_t)g * CH * N_EXP;
#pragma unroll
        for (int k = 0; k < CH; ++k) {
            const float* wk = wg + (size_t)k * N_EXP;  // uniform -> s_load
            const float xk = xc[k];
#pragma unroll
            for (int e = 0; e < 32; ++e)
                acc[e] = fmaf(wk[e], xk, acc[e]);
        }
    };

    float4 a0 = *(const float4*)(xr + 0);
    float4 a1 = *(const float4*)(xr + 4);
    float4 a2 = *(const float4*)(xr + 8);
    float4 a3 = *(const float4*)(xr + 12);

#pragma unroll 1
    for (int g = 0; g < NCH; g += 2) {
        // prefetch chunk g+1 (always valid: g+1 <= NCH-1)
        const float* xb = xr + (size_t)(g + 1) * CH;
        float4 b0 = *(const float4*)(xb + 0);
        float4 b1 = *(const float4*)(xb + 4);
        float4 b2 = *(const float4*)(xb + 8);
        float4 b3 = *(const float4*)(xb + 12);

        fma_chunk(a0, a1, a2, a3, g);

        // prefetch chunk g+2, wrapped (last iter harmlessly re-reads chunk 0)
        const float* xa = xr + (size_t)((g + 2) & (NCH - 1)) * CH;
        a0 = *(const float4*)(xa + 0);
        a1 = *(const float4*)(xa + 4);
        a2 = *(const float4*)(xa + 8);
        a3 = *(const float4*)(xa + 12);

        fma_chunk(b0, b1, b2, b3, g + 1);
    }

    // ---- epilogue: k-slice reduce + softmax/top2 (round-8, verified) ----
    {
        float* tp = part + (size_t)(wid * TOKB + lane) * PPAD;
#pragma unroll
        for (int e0 = 0; e0 < 32; e0 += 4)
            *(float4*)(tp + e0) = make_float4(acc[e0], acc[e0 + 1],
                                              acc[e0 + 2], acc[e0 + 3]);
    }
    __syncthreads();

    float p_acc = 0.f, f_acc = 0.f;          // lane = expert now
    const int he = lane >> 5;                // this expert's half
    const int ew = lane & 31;
#pragma unroll 1
    for (int it = 0; it < 4; ++it) {
        const int tl = wid * 4 + it;         // local token (16 waves x 4)
        float logit = 0.f;
#pragma unroll
        for (int sl = 0; sl < NSL; ++sl)
            logit += part[(size_t)((2 * sl + he) * TOKB + tl) * PPAD + ew];

        // top-1: value max-reduce, then ballot -> lowest tied index
        float m = logit;
#pragma unroll
        for (int off = 32; off; off >>= 1)
            m = fmaxf(m, __shfl_xor(m, off, 64));
        unsigned long long b1 = __ballot(logit == m);
        int i1 = __ffsll(b1) - 1;

        float p = expf(logit - m);
        float denom = p;
#pragma unroll
        for (int off = 32; off; off >>= 1)
            denom += __shfl_xor(denom, off, 64);

        p_acc += p / denom;                  // router_probs[token][lane]
        if (lane == i1) f_acc += 1.f;

        // top-2: mask i1, repeat
        float lx = (lane == i1) ? -__builtin_inff() : logit;
        float m2 = lx;
#pragma unroll
        for (int off = 32; off; off >>= 1)
            m2 = fmaxf(m2, __shfl_xor(m2, off, 64));
        unsigned long long b2 = __ballot(lx == m2);
        int i2 = __ffsll(b2) - 1;

        if (lane == 0) {
            float p1 = 1.0f / denom;                 // exp(m-m)/denom
            float p2 = expf(m2 - m) / denom;
            float s12 = p1 + p2;
            int token = tok0 + tl;
            ((float2*)out)[token] = make_float2(p1 / s12, p2 / s12);
            ((float2*)(out + 2 * N_TOKENS))[token] =
                make_float2((float)i1, (float)i2);
        }
    }

    // block-level p/f sums -> block_sums (no atomics)
    float* pf = part + PFOFF;                // [0,1024): p, [1024,2048): f
    pf[wid * 64 + lane]        = p_acc;
    pf[1024 + wid * 64 + lane] = f_acc;
    __syncthreads();
    if (tid < N_EXP) {
        float ps = 0.f, fs = 0.f;
#pragma unroll
        for (int hh = 0; hh < NWV; ++hh) {
            ps += pf[hh * 64 + tid];
            fs += pf[1024 + hh * 64 + tid];
        }
        block_sums[(size_t)blockIdx.x * 128 + tid]      = ps;
        block_sums[(size_t)blockIdx.x * 128 + 64 + tid] = fs;
    }
}

// ---------------------------------------------------------------------------
// Final: reduce 256 blocks' p/f sums, loss = 0.01 * sum_e (f_e/N)*(p_e/N).
// ---------------------------------------------------------------------------
__global__ void __launch_bounds__(256)
router_final(const float* __restrict__ block_sums, float* __restrict__ out) {
    __shared__ float sp[4][N_EXP];
    __shared__ float sf[4][N_EXP];

    int tid  = threadIdx.x;
    int wv   = tid >> 6;
    int lane = tid & 63;

    float ps = 0.f, fs = 0.f;
#pragma unroll 8
    for (int b = wv * (NBLK / 4); b < (wv + 1) * (NBLK / 4); ++b) {
        ps += block_sums[(size_t)b * 128 + lane];
        fs += block_sums[(size_t)b * 128 + 64 + lane];
    }
    sp[wv][lane] = ps;
    sf[wv][lane] = fs;
    __syncthreads();

    if (tid < N_EXP) {
        float pt = sp[0][tid] + sp[1][tid] + sp[2][tid] + sp[3][tid];
        float ft = sf[0][tid] + sf[1][tid] + sf[2][tid] + sf[3][tid];
        float v = pt * ft;
#pragma unroll
        for (int off = 1; off < 64; off <<= 1)
            v += __shfl_xor(v, off, 64);
        if (tid == 0)
            out[4 * N_TOKENS] = 0.01f * v / ((float)N_TOKENS * (float)N_TOKENS);
    }
}

// ---------------------------------------------------------------------------
extern "C" void kernel_launch(void* const* d_in, const int* in_sizes, int n_in,
                              void* d_out, int out_size, void* d_ws, size_t ws_size,
                              hipStream_t stream) {
    (void)in_sizes; (void)n_in; (void)out_size; (void)ws_size;
    const float* x = (const float*)d_in[0];
    const float* w = (const float*)d_in[1];
    float* out = (float*)d_out;

    float* wT = (float*)d_ws;                            // 4096*64*4 = 1 MB
    float* block_sums = wT + (size_t)D_MODEL * N_EXP;    // 256*128*4 = 128 KB

    transpose_w<<<D_MODEL / 64, 256, 0, stream>>>(w, wT);
    router_fused<<<NBLK, 1024, 0, stream>>>(x, wT, out, block_sums);
    router_final<<<1, 256, 0, stream>>>(block_sums, out);
}

// Round 11
// 418.097 us; speedup vs baseline: 12.7970x; 12.7970x over previous
//
#include <hip/hip_runtime.h>
#include <math.h>

#define N_TOKENS 16384
#define D_MODEL  4096
#define N_EXP    64

#define TOKB  64                 // tokens per block (lane = token)
#define NWV   16                 // waves per block (1024 threads)
#define NSL   8                  // k-slices
#define KSL   (D_MODEL / NSL)    // 512 k per wave
#define CH    16                 // k per chunk (= 64 B per-lane line)
#define NCH   (KSL / CH)         // 32 chunks
#define PPAD  36                 // partial-tile expert stride (conflict-free)
#define PFOFF (NWV * TOKB * PPAD) // 36864 floats
#define NBLK  (N_TOKENS / TOKB)  // 256 blocks = 1/CU -> 16 waves/CU = 4/SIMD

// ---------------------------------------------------------------------------
// Pre-pass: w[64][4096] -> wT[4096][64] (k-major). A k-row's 64 experts are
// contiguous -> per-k expert-half = 32 uniform floats -> s_load_dwordx16.
// ---------------------------------------------------------------------------
__global__ void __launch_bounds__(256)
transpose_w(const float* __restrict__ w, float* __restrict__ wt) {
    __shared__ float t[64][65];
    const int k0 = blockIdx.x * 64;
    const int kc = (threadIdx.x & 15) * 4;
    const int e0 = threadIdx.x >> 4;         // 0..15
#pragma unroll
    for (int p = 0; p < 4; ++p) {
        int e = p * 16 + e0;
        float4 v = *(const float4*)(w + (size_t)e * D_MODEL + k0 + kc);
        t[kc + 0][e] = v.x; t[kc + 1][e] = v.y;
        t[kc + 2][e] = v.z; t[kc + 3][e] = v.w;
    }
    __syncthreads();
    const int kr = threadIdx.x >> 2;         // 0..63
    const int ec = (threadIdx.x & 3) * 16;
#pragma unroll
    for (int j = 0; j < 4; ++j) {
        float4 v = make_float4(t[kr][ec + j * 4 + 0], t[kr][ec + j * 4 + 1],
                               t[kr][ec + j * 4 + 2], t[kr][ec + j * 4 + 3]);
        *(float4*)(wt + (size_t)(k0 + kr) * N_EXP + ec + j * 4) = v;
    }
}

// ---------------------------------------------------------------------------
// Fused router — round-8 structure, prefetch guard removed (nothing else).
// Evidence base: round 8's VALU-busy TIME (0.38 x 165us = 63us) ~= the
// 54.6us FMA floor -> its instruction stream is near-ideal; the loss was
// the compiler sinking the `if (g+1<NCH)` guarded prefetch to the loop
// tail (VGPR=52: no double-buffer held) -> serial ~900cy HBM latency per
// chunk. Round 10's lambda+local-array rewrite stack-allocated the working
// set (FETCH 3GB, VALU 2.4%) — so this version is strictly straight-line:
//   - loop bound NCH-1 makes the next-chunk load UNCONDITIONAL (no guard
//     to sink); last chunk computed in an epilogue after the loop
//   - no lambda, no local arrays: 16 explicit k-steps on .x/.y/.z/.w,
//     acc[] indexed only by unrolled constants
//   - lane = token; x via per-lane global_load_dwordx4 (vector path)
//   - w via scalar pipe: per k-row 32 uniform floats from L2-hot wT
//   - NO DS ops in the main loop (SMEM waits stay precise)
// Epilogue (verbatim round 8): 16 partial tiles [64 tok][32 exp] stride 36
// in LDS, 8-slice reduce, ballot-argmax softmax/top-2, per-block p/f sums.
// ---------------------------------------------------------------------------
__global__ void __launch_bounds__(1024)
router_fused(const float* __restrict__ x, const float* __restrict__ wt,
             float* __restrict__ out, float* __restrict__ block_sums) {
    __shared__ float part[PFOFF + 2 * NWV * 64];   // 147456 + 8192 B

    const int tid  = threadIdx.x;
    const int wid  = tid >> 6;
    const int lane = tid & 63;               // token within block
    const int tok0 = blockIdx.x * TOKB;

    const int wid_u = __builtin_amdgcn_readfirstlane(wid);
    const int h = wid_u & 1;                 // expert half: experts h*32..+31
    const int s = wid_u >> 1;                // k-slice: k in [s*512, s*512+512)

    const float* xr = x + (size_t)(tok0 + lane) * D_MODEL + s * KSL;
    const float* wr = wt + (size_t)s * KSL * N_EXP + h * 32;   // uniform

    float acc[32] = {};

#define K_STEP(wg, kidx, xv) do {                              \
        const float* wk_ = (wg) + (kidx) * N_EXP;              \
        const float xk_ = (xv);                                \
        _Pragma("unroll")                                      \
        for (int e = 0; e < 32; ++e)                           \
            acc[e] = fmaf(wk_[e], xk_, acc[e]);                \
    } while (0)

#define CHUNK_FMA(g, q0, q1, q2, q3) do {                      \
        const float* wg_ = wr + (size_t)(g) * CH * N_EXP;      \
        K_STEP(wg_,  0, (q0).x); K_STEP(wg_,  1, (q0).y);      \
        K_STEP(wg_,  2, (q0).z); K_STEP(wg_,  3, (q0).w);      \
        K_STEP(wg_,  4, (q1).x); K_STEP(wg_,  5, (q1).y);      \
        K_STEP(wg_,  6, (q1).z); K_STEP(wg_,  7, (q1).w);      \
        K_STEP(wg_,  8, (q2).x); K_STEP(wg_,  9, (q2).y);      \
        K_STEP(wg_, 10, (q2).z); K_STEP(wg_, 11, (q2).w);      \
        K_STEP(wg_, 12, (q3).x); K_STEP(wg_, 13, (q3).y);      \
        K_STEP(wg_, 14, (q3).z); K_STEP(wg_, 15, (q3).w);      \
    } while (0)

    float4 c0 = *(const float4*)(xr + 0);
    float4 c1 = *(const float4*)(xr + 4);
    float4 c2 = *(const float4*)(xr + 8);
    float4 c3 = *(const float4*)(xr + 12);

#pragma unroll 1
    for (int g = 0; g < NCH - 1; ++g) {
        const float* xn = xr + (size_t)(g + 1) * CH;   // always in-bounds
        float4 n0 = *(const float4*)(xn + 0);
        float4 n1 = *(const float4*)(xn + 4);
        float4 n2 = *(const float4*)(xn + 8);
        float4 n3 = *(const float4*)(xn + 12);

        CHUNK_FMA(g, c0, c1, c2, c3);

        c0 = n0; c1 = n1; c2 = n2; c3 = n3;
    }
    CHUNK_FMA(NCH - 1, c0, c1, c2, c3);

    // ---- epilogue: k-slice reduce + softmax/top2 (round-8, verified) ----
    {
        float* tp = part + (size_t)(wid * TOKB + lane) * PPAD;
#pragma unroll
        for (int e0 = 0; e0 < 32; e0 += 4)
            *(float4*)(tp + e0) = make_float4(acc[e0], acc[e0 + 1],
                                              acc[e0 + 2], acc[e0 + 3]);
    }
    __syncthreads();

    float p_acc = 0.f, f_acc = 0.f;          // lane = expert now
    const int he = lane >> 5;                // this expert's half
    const int ew = lane & 31;
#pragma unroll 1
    for (int it = 0; it < 4; ++it) {
        const int tl = wid * 4 + it;         // local token (16 waves x 4)
        float logit = 0.f;
#pragma unroll
        for (int sl = 0; sl < NSL; ++sl)
            logit += part[(size_t)((2 * sl + he) * TOKB + tl) * PPAD + ew];

        // top-1: value max-reduce, then ballot -> lowest tied index
        float m = logit;
#pragma unroll
        for (int off = 32; off; off >>= 1)
            m = fmaxf(m, __shfl_xor(m, off, 64));
        unsigned long long b1 = __ballot(logit == m);
        int i1 = __ffsll(b1) - 1;

        float p = expf(logit - m);
        float denom = p;
#pragma unroll
        for (int off = 32; off; off >>= 1)
            denom += __shfl_xor(denom, off, 64);

        p_acc += p / denom;                  // router_probs[token][lane]
        if (lane == i1) f_acc += 1.f;

        // top-2: mask i1, repeat
        float lx = (lane == i1) ? -__builtin_inff() : logit;
        float m2 = lx;
#pragma unroll
        for (int off = 32; off; off >>= 1)
            m2 = fmaxf(m2, __shfl_xor(m2, off, 64));
        unsigned long long b2 = __ballot(lx == m2);
        int i2 = __ffsll(b2) - 1;

        if (lane == 0) {
            float p1 = 1.0f / denom;                 // exp(m-m)/denom
            float p2 = expf(m2 - m) / denom;
            float s12 = p1 + p2;
            int token = tok0 + tl;
            ((float2*)out)[token] = make_float2(p1 / s12, p2 / s12);
            ((float2*)(out + 2 * N_TOKENS))[token] =
                make_float2((float)i1, (float)i2);
        }
    }

    // block-level p/f sums -> block_sums (no atomics)
    float* pf = part + PFOFF;                // [0,1024): p, [1024,2048): f
    pf[wid * 64 + lane]        = p_acc;
    pf[1024 + wid * 64 + lane] = f_acc;
    __syncthreads();
    if (tid < N_EXP) {
        float ps = 0.f, fs = 0.f;
#pragma unroll
        for (int hh = 0; hh < NWV; ++hh) {
            ps += pf[hh * 64 + tid];
            fs += pf[1024 + hh * 64 + tid];
        }
        block_sums[(size_t)blockIdx.x * 128 + tid]      = ps;
        block_sums[(size_t)blockIdx.x * 128 + 64 + tid] = fs;
    }
}

// ---------------------------------------------------------------------------
// Final: reduce 256 blocks' p/f sums, loss = 0.01 * sum_e (f_e/N)*(p_e/N).
// ---------------------------------------------------------------------------
__global__ void __launch_bounds__(256)
router_final(const float* __restrict__ block_sums, float* __restrict__ out) {
    __shared__ float sp[4][N_EXP];
    __shared__ float sf[4][N_EXP];

    int tid  = threadIdx.x;
    int wv   = tid >> 6;
    int lane = tid & 63;

    float ps = 0.f, fs = 0.f;
#pragma unroll 8
    for (int b = wv * (NBLK / 4); b < (wv + 1) * (NBLK / 4); ++b) {
        ps += block_sums[(size_t)b * 128 + lane];
        fs += block_sums[(size_t)b * 128 + 64 + lane];
    }
    sp[wv][lane] = ps;
    sf[wv][lane] = fs;
    __syncthreads();

    if (tid < N_EXP) {
        float pt = sp[0][tid] + sp[1][tid] + sp[2][tid] + sp[3][tid];
        float ft = sf[0][tid] + sf[1][tid] + sf[2][tid] + sf[3][tid];
        float v = pt * ft;
#pragma unroll
        for (int off = 1; off < 64; off <<= 1)
            v += __shfl_xor(v, off, 64);
        if (tid == 0)
            out[4 * N_TOKENS] = 0.01f * v / ((float)N_TOKENS * (float)N_TOKENS);
    }
}

// ---------------------------------------------------------------------------
extern "C" void kernel_launch(void* const* d_in, const int* in_sizes, int n_in,
                              void* d_out, int out_size, void* d_ws, size_t ws_size,
                              hipStream_t stream) {
    (void)in_sizes; (void)n_in; (void)out_size; (void)ws_size;
    const float* x = (const float*)d_in[0];
    const float* w = (const float*)d_in[1];
    float* out = (float*)d_out;

    float* wT = (float*)d_ws;                            // 4096*64*4 = 1 MB
    float* block_sums = wT + (size_t)D_MODEL * N_EXP;    // 256*128*4 = 128 KB

    transpose_w<<<D_MODEL / 64, 256, 0, stream>>>(w, wT);
    router_fused<<<NBLK, 1024, 0, stream>>>(x, wT, out, block_sums);
    router_final<<<1, 256, 0, stream>>>(block_sums, out);
}